// Round 5
// baseline (626.517 us; speedup 1.0000x reference)
//
#include <hip/hip_runtime.h>

#define LEAK 0.2f

static inline size_t align256(size_t x) { return (x + 255) & ~size_t(255); }

__device__ inline float readlane_f(float v, int l) {
    return __uint_as_float((unsigned)__builtin_amdgcn_readlane(__float_as_uint(v), l));
}

// ---------------- CSR build (real edges only; self-loops handled analytically) ----------------
__global__ void k_count(const int* __restrict__ edst, int E, int* __restrict__ deg) {
    for (int k = blockIdx.x * blockDim.x + threadIdx.x; k < E; k += gridDim.x * blockDim.x)
        atomicAdd(&deg[edst[k]], 1);
}

// ---- hierarchical scan: phase 1 — per-256-chunk sums ----
__global__ __launch_bounds__(256) void k_scan_partial(const int* __restrict__ deg, int N,
                                                      int* __restrict__ partial) {
    __shared__ int red[4];
    int i = blockIdx.x * 256 + threadIdx.x;
    int v = (i < N) ? deg[i] : 0;
#pragma unroll
    for (int off = 32; off; off >>= 1) v += __shfl_xor(v, off);
    int lane = threadIdx.x & 63, w = threadIdx.x >> 6;
    if (lane == 0) red[w] = v;
    __syncthreads();
    if (threadIdx.x == 0) partial[blockIdx.x] = red[0] + red[1] + red[2] + red[3];
}

// ---- phase 2 — single block scans the partials (B <= 1024) ----
__global__ __launch_bounds__(1024) void k_scan_top(int* __restrict__ partial, int B) {
    __shared__ int buf[1024];
    int tid = threadIdx.x;
    int v = (tid < B) ? partial[tid] : 0;
    buf[tid] = v;
    __syncthreads();
    for (int off = 1; off < 1024; off <<= 1) {
        int t = buf[tid];
        int add = (tid >= off) ? buf[tid - off] : 0;
        __syncthreads();
        buf[tid] = t + add;
        __syncthreads();
    }
    if (tid < B) partial[tid] = buf[tid] - v;   // exclusive
}

// ---- phase 3 — per-chunk inclusive scan + chunk offset -> rowptr ----
__global__ __launch_bounds__(256) void k_scan_final(const int* __restrict__ deg, int N,
                                                    const int* __restrict__ partial,
                                                    int* __restrict__ rowptr) {
    __shared__ int buf[256];
    int tid = threadIdx.x;
    int i = blockIdx.x * 256 + tid;
    int v = (i < N) ? deg[i] : 0;
    buf[tid] = v;
    __syncthreads();
    for (int off = 1; off < 256; off <<= 1) {
        int t = buf[tid];
        int add = (tid >= off) ? buf[tid - off] : 0;
        __syncthreads();
        buf[tid] = t + add;
        __syncthreads();
    }
    if (i < N) rowptr[i + 1] = partial[blockIdx.x] + buf[tid];
    if (i == 0) rowptr[0] = 0;
}

__global__ void k_scatter(const int* __restrict__ esrc, const int* __restrict__ edst,
                          int E, const int* __restrict__ rowptr,
                          int* __restrict__ cursor, int* __restrict__ csr_src) {
    for (int k = blockIdx.x * blockDim.x + threadIdx.x; k < E; k += gridDim.x * blockDim.x) {
        int s = esrc[k], d = edst[k];
        int pos = atomicAdd(&cursor[d], 1);
        csr_src[rowptr[d] + pos] = s;
    }
}

// ------- GEMM: h[N,128] = x[N,128] @ W[128,128], fused alpha1 dots -------
__global__ __launch_bounds__(256) void k_gemm128(const float* __restrict__ x,
                                                 const float* __restrict__ W,
                                                 const float* __restrict__ avs,
                                                 const float* __restrict__ avd,
                                                 float* __restrict__ h,
                                                 float* __restrict__ as, float* __restrict__ ad,
                                                 int N) {
    __shared__ float sW[128 * 128];
    __shared__ float sX[32 * 128];
    int tid = threadIdx.x;
    const float4* W4 = (const float4*)W;
    float4* sW4 = (float4*)sW;
#pragma unroll
    for (int i = 0; i < 16; ++i) sW4[tid + i * 256] = W4[tid + i * 256];

    int row0 = blockIdx.x * 32;
    int lr = tid >> 5;       // 0..7
    int lk = tid & 31;       // float4 index within row
    const float4* x4 = (const float4*)x;
    float4* sX4 = (float4*)sX;
#pragma unroll
    for (int i = 0; i < 4; ++i) {
        int r = lr + i * 8;
        int gr = row0 + r; if (gr > N - 1) gr = N - 1;
        sX4[r * 32 + lk] = x4[gr * 32 + lk];
    }
    __syncthreads();

    int tr = (tid >> 5) * 4;    // 4 rows
    int tc = (tid & 31) * 4;    // 4 cols
    float acc[4][4] = {};
#pragma unroll
    for (int kb = 0; kb < 32; ++kb) {
        int k0 = kb * 4;
        float4 xv0 = *(const float4*)&sX[(tr + 0) * 128 + k0];
        float4 xv1 = *(const float4*)&sX[(tr + 1) * 128 + k0];
        float4 xv2 = *(const float4*)&sX[(tr + 2) * 128 + k0];
        float4 xv3 = *(const float4*)&sX[(tr + 3) * 128 + k0];
        float4 w0 = *(const float4*)&sW[(k0 + 0) * 128 + tc];
        float4 w1 = *(const float4*)&sW[(k0 + 1) * 128 + tc];
        float4 w2 = *(const float4*)&sW[(k0 + 2) * 128 + tc];
        float4 w3 = *(const float4*)&sW[(k0 + 3) * 128 + tc];
#define FMA_ROW(i, xv)                                                                              \
        acc[i][0] += xv.x * w0.x; acc[i][1] += xv.x * w0.y; acc[i][2] += xv.x * w0.z; acc[i][3] += xv.x * w0.w; \
        acc[i][0] += xv.y * w1.x; acc[i][1] += xv.y * w1.y; acc[i][2] += xv.y * w1.z; acc[i][3] += xv.y * w1.w; \
        acc[i][0] += xv.z * w2.x; acc[i][1] += xv.z * w2.y; acc[i][2] += xv.z * w2.z; acc[i][3] += xv.z * w2.w; \
        acc[i][0] += xv.w * w3.x; acc[i][1] += xv.w * w3.y; acc[i][2] += xv.w * w3.z; acc[i][3] += xv.w * w3.w;
        FMA_ROW(0, xv0)
        FMA_ROW(1, xv1)
        FMA_ROW(2, xv2)
        FMA_ROW(3, xv3)
#undef FMA_ROW
    }
    float4 vs = *(const float4*)&avs[tc];
    float4 vd = *(const float4*)&avd[tc];
#pragma unroll
    for (int i = 0; i < 4; ++i) {
        int gr = row0 + tr + i;
        if (gr < N) {
            float4 o; o.x = acc[i][0]; o.y = acc[i][1]; o.z = acc[i][2]; o.w = acc[i][3];
            *(float4*)&h[gr * 128 + tc] = o;
        }
        float ps = acc[i][0]*vs.x + acc[i][1]*vs.y + acc[i][2]*vs.z + acc[i][3]*vs.w;
        float pd = acc[i][0]*vd.x + acc[i][1]*vd.y + acc[i][2]*vd.z + acc[i][3]*vd.w;
#pragma unroll
        for (int off = 16; off; off >>= 1) {
            ps += __shfl_xor(ps, off);
            pd += __shfl_xor(pd, off);
        }
        if ((tid & 31) == 0 && gr < N) { as[gr] = ps; ad[gr] = pd; }
    }
}

// ---- layer-1 aggregation + ReLU + GEMM16 + alpha2, one wave per dst node ----
__global__ __launch_bounds__(256) void k_agg128f(const float* __restrict__ h,
                                                 const float* __restrict__ as,
                                                 const float* __restrict__ ad,
                                                 const float* __restrict__ b1,
                                                 const float* __restrict__ W2,
                                                 const float* __restrict__ avs2,
                                                 const float* __restrict__ avd2,
                                                 const int* __restrict__ rowptr,
                                                 const int* __restrict__ csr_src,
                                                 float* __restrict__ h2,
                                                 float* __restrict__ as2, float* __restrict__ ad2,
                                                 int N) {
    __shared__ float gbuf[4][128];
    int wid = (blockIdx.x * blockDim.x + threadIdx.x) >> 6;
    int lane = threadIdx.x & 63;
    int wib = threadIdx.x >> 6;
    if (wid >= N) return;
    int start = rowptr[wid], end = rowptr[wid + 1];
    int deg = end - start;                 // real in-edges (self-loop handled inline)
    float adv = ad[wid];

    // per-lane edge (first 64)
    int s_l = 0; float e_l = -1e30f;
    if (lane < deg) {
        s_l = csr_src[start + lane];
        float e = as[s_l] + adv;
        e_l = e > 0.f ? e : LEAK * e;
    }
    // max over all edges
    float m = e_l;
    for (int j = start + 64 + lane; j < end; j += 64) {
        int s = csr_src[j];
        float e = as[s] + adv;
        e = e > 0.f ? e : LEAK * e;
        m = fmaxf(m, e);
    }
#pragma unroll
    for (int off = 32; off; off >>= 1) m = fmaxf(m, __shfl_xor(m, off));
    float es = as[wid] + adv;              // self-loop score
    es = es > 0.f ? es : LEAK * es;
    m = fmaxf(m, es);

    // all 64 exps in one vector op; denom by butterfly (inactive lanes -> 0)
    float w_l = __expf(e_l - m);
    float dsum = w_l;
#pragma unroll
    for (int off = 32; off; off >>= 1) dsum += __shfl_xor(dsum, off);

    const float2* hrow = (const float2*)h;     // rows of 64 float2
    float2 a0 = make_float2(0.f, 0.f), a1 = a0, a2 = a0, a3 = a0;
    int dmain = deg < 64 ? deg : 64;
    int j = 0;
    for (; j + 4 <= dmain; j += 4) {
        int s0 = __builtin_amdgcn_readlane(s_l, j);
        int s1 = __builtin_amdgcn_readlane(s_l, j + 1);
        int s2 = __builtin_amdgcn_readlane(s_l, j + 2);
        int s3 = __builtin_amdgcn_readlane(s_l, j + 3);
        float w0 = readlane_f(w_l, j);
        float w1 = readlane_f(w_l, j + 1);
        float w2 = readlane_f(w_l, j + 2);
        float w3 = readlane_f(w_l, j + 3);
        float2 v0 = hrow[(size_t)s0 * 64 + lane];
        float2 v1 = hrow[(size_t)s1 * 64 + lane];
        float2 v2 = hrow[(size_t)s2 * 64 + lane];
        float2 v3 = hrow[(size_t)s3 * 64 + lane];
        a0.x += w0 * v0.x; a0.y += w0 * v0.y;
        a1.x += w1 * v1.x; a1.y += w1 * v1.y;
        a2.x += w2 * v2.x; a2.y += w2 * v2.y;
        a3.x += w3 * v3.x; a3.y += w3 * v3.y;
    }
    for (; j < dmain; ++j) {
        int s0 = __builtin_amdgcn_readlane(s_l, j);
        float w0 = readlane_f(w_l, j);
        float2 v0 = hrow[(size_t)s0 * 64 + lane];
        a0.x += w0 * v0.x; a0.y += w0 * v0.y;
    }
    // tail edges beyond 64 (rare)
    for (int jj = start + 64; jj < end; ++jj) {
        int s = csr_src[jj];               // wave-uniform
        float e = as[s] + adv;
        e = e > 0.f ? e : LEAK * e;
        float w = __expf(e - m);
        dsum += w;
        float2 v = hrow[(size_t)s * 64 + lane];
        a0.x += w * v.x; a0.y += w * v.y;
    }
    // self-loop
    {
        float w = __expf(es - m);
        dsum += w;
        float2 v = hrow[(size_t)wid * 64 + lane];
        a0.x += w * v.x; a0.y += w * v.y;
    }
    float accx = (a0.x + a1.x) + (a2.x + a3.x);
    float accy = (a0.y + a1.y) + (a2.y + a3.y);

    float inv = 1.0f / dsum;
    float2 bb = ((const float2*)b1)[lane];
    float gx = fmaxf(accx * inv + bb.x, 0.f);   // fused ReLU
    float gy = fmaxf(accy * inv + bb.y, 0.f);
    ((float2*)gbuf[wib])[lane] = make_float2(gx, gy);

    // h2 row = g @ W2 (128x16): lane = (q<<4)|c
    int q = lane >> 4, c = lane & 15;
    float p = 0.f;
#pragma unroll
    for (int kk = 0; kk < 32; ++kk) {
        int k = kk * 4 + q;
        p += gbuf[wib][k] * W2[k * 16 + c];
    }
    p += __shfl_xor(p, 16);
    p += __shfl_xor(p, 32);          // all lanes: h2 value for col c
    if (lane < 16) h2[wid * 16 + c] = p;
    float ps = p * avs2[c];
    float pd = p * avd2[c];
#pragma unroll
    for (int off = 8; off; off >>= 1) {
        ps += __shfl_xor(ps, off);
        pd += __shfl_xor(pd, off);
    }
    if (lane == 0) { as2[wid] = ps; ad2[wid] = pd; }
}

// ---- layer-2 aggregation: 16 lanes per node, serial over edges ----
__global__ __launch_bounds__(256) void k_agg16(const float* __restrict__ h2,
                                               const float* __restrict__ as,
                                               const float* __restrict__ ad,
                                               const float* __restrict__ bias,
                                               const int* __restrict__ rowptr,
                                               const int* __restrict__ csr_src,
                                               float* __restrict__ out, int N) {
    int grp = (blockIdx.x * blockDim.x + threadIdx.x) >> 4;  // node id
    int c = threadIdx.x & 15;
    if (grp >= N) return;
    int start = rowptr[grp], end = rowptr[grp + 1];
    float adv = ad[grp];
    float es = as[grp] + adv;              // self-loop
    es = es > 0.f ? es : LEAK * es;
    float m = es;
    for (int j = start; j < end; ++j) {
        int s = csr_src[j];                // broadcast across 16 lanes
        float e = as[s] + adv;
        e = e > 0.f ? e : LEAK * e;
        m = fmaxf(m, e);
    }
    float ws = __expf(es - m);
    float dsum = ws;
    float acc = ws * h2[grp * 16 + c];
    for (int j = start; j < end; ++j) {
        int s = csr_src[j];
        float e = as[s] + adv;
        e = e > 0.f ? e : LEAK * e;
        float w = __expf(e - m);
        dsum += w;
        acc += w * h2[s * 16 + c];
    }
    out[grp * 16 + c] = acc / dsum + bias[c];
}

extern "C" void kernel_launch(void* const* d_in, const int* in_sizes, int n_in,
                              void* d_out, int out_size, void* d_ws, size_t ws_size,
                              hipStream_t stream) {
    const float* x    = (const float*)d_in[0];
    const int*   ei   = (const int*)d_in[1];
    const float* W1   = (const float*)d_in[2];
    const float* avs1 = (const float*)d_in[3];
    const float* avd1 = (const float*)d_in[4];
    const float* b1   = (const float*)d_in[5];
    const float* W2   = (const float*)d_in[6];
    const float* avs2 = (const float*)d_in[7];
    const float* avd2 = (const float*)d_in[8];
    const float* b2   = (const float*)d_in[9];

    int N = in_sizes[0] / 128;
    int E = in_sizes[1] / 2;
    const int* esrc = ei;
    const int* edst = ei + E;

    char* p = (char*)d_ws;
    auto carve = [&](size_t bytes) { char* r = p; p += align256(bytes); return r; };
    float* h1     = (float*)carve(sizeof(float) * (size_t)N * 128);
    float* h2     = (float*)carve(sizeof(float) * (size_t)N * 16);
    float* as1    = (float*)carve(sizeof(float) * N);
    float* ad1    = (float*)carve(sizeof(float) * N);
    float* as2    = (float*)carve(sizeof(float) * N);
    float* ad2    = (float*)carve(sizeof(float) * N);
    int* rowptr   = (int*)carve(sizeof(int) * (N + 1));
    int* degcur   = (int*)carve(sizeof(int) * 2 * (size_t)N);
    int* deg = degcur; int* cursor = degcur + N;
    int* partial  = (int*)carve(sizeof(int) * 1024);
    int* csr_src  = (int*)carve(sizeof(int) * (size_t)E);

    hipMemsetAsync(degcur, 0, sizeof(int) * 2 * (size_t)N, stream);
    k_count<<<2048, 256, 0, stream>>>(edst, E, deg);

    int B = (N + 255) / 256;
    k_scan_partial<<<B, 256, 0, stream>>>(deg, N, partial);
    k_scan_top<<<1, 1024, 0, stream>>>(partial, B);
    k_scan_final<<<B, 256, 0, stream>>>(deg, N, partial, rowptr);

    k_scatter<<<2048, 256, 0, stream>>>(esrc, edst, E, rowptr, cursor, csr_src);

    int gGemm = (N + 31) / 32;
    k_gemm128<<<gGemm, 256, 0, stream>>>(x, W1, avs1, avd1, h1, as1, ad1, N);
    int gWave = (N * 64 + 255) / 256;
    k_agg128f<<<gWave, 256, 0, stream>>>(h1, as1, ad1, b1, W2, avs2, avd2,
                                         rowptr, csr_src, h2, as2, ad2, N);
    int gAgg16 = (N * 16 + 255) / 256;
    k_agg16<<<gAgg16, 256, 0, stream>>>(h2, as2, ad2, b2, rowptr, csr_src, (float*)d_out, N);
}

// Round 6
// 225.258 us; speedup vs baseline: 2.7813x; 2.7813x over previous
//
#include <hip/hip_runtime.h>

#define LEAK 0.2f

static inline size_t align256(size_t x) { return (x + 255) & ~size_t(255); }

__device__ inline float readlane_f(float v, int l) {
    return __uint_as_float((unsigned)__builtin_amdgcn_readlane(__float_as_uint(v), l));
}

// ---------------- CSR build (real edges only; self-loops handled analytically) ----------------
__global__ void k_count(const int* __restrict__ edst, int E, int* __restrict__ deg) {
    for (int k = blockIdx.x * blockDim.x + threadIdx.x; k < E; k += gridDim.x * blockDim.x)
        atomicAdd(&deg[edst[k]], 1);
}

// ---- hierarchical scan: phase 1 — per-256-chunk sums ----
__global__ __launch_bounds__(256) void k_scan_partial(const int* __restrict__ deg, int N,
                                                      int* __restrict__ partial) {
    __shared__ int red[4];
    int i = blockIdx.x * 256 + threadIdx.x;
    int v = (i < N) ? deg[i] : 0;
#pragma unroll
    for (int off = 32; off; off >>= 1) v += __shfl_xor(v, off);
    int lane = threadIdx.x & 63, w = threadIdx.x >> 6;
    if (lane == 0) red[w] = v;
    __syncthreads();
    if (threadIdx.x == 0) partial[blockIdx.x] = red[0] + red[1] + red[2] + red[3];
}

// ---- phase 2 — single block scans the partials (B <= 1024) ----
__global__ __launch_bounds__(1024) void k_scan_top(int* __restrict__ partial, int B) {
    __shared__ int buf[1024];
    int tid = threadIdx.x;
    int v = (tid < B) ? partial[tid] : 0;
    buf[tid] = v;
    __syncthreads();
    for (int off = 1; off < 1024; off <<= 1) {
        int t = buf[tid];
        int add = (tid >= off) ? buf[tid - off] : 0;
        __syncthreads();
        buf[tid] = t + add;
        __syncthreads();
    }
    if (tid < B) partial[tid] = buf[tid] - v;   // exclusive
}

// ---- phase 3 — per-chunk inclusive scan + chunk offset -> rowptr ----
__global__ __launch_bounds__(256) void k_scan_final(const int* __restrict__ deg, int N,
                                                    const int* __restrict__ partial,
                                                    int* __restrict__ rowptr) {
    __shared__ int buf[256];
    int tid = threadIdx.x;
    int i = blockIdx.x * 256 + tid;
    int v = (i < N) ? deg[i] : 0;
    buf[tid] = v;
    __syncthreads();
    for (int off = 1; off < 256; off <<= 1) {
        int t = buf[tid];
        int add = (tid >= off) ? buf[tid - off] : 0;
        __syncthreads();
        buf[tid] = t + add;
        __syncthreads();
    }
    if (i < N) rowptr[i + 1] = partial[blockIdx.x] + buf[tid];
    if (i == 0) rowptr[0] = 0;
}

__global__ void k_scatter(const int* __restrict__ esrc, const int* __restrict__ edst,
                          int E, const int* __restrict__ rowptr,
                          int* __restrict__ cursor, int* __restrict__ csr_src) {
    for (int k = blockIdx.x * blockDim.x + threadIdx.x; k < E; k += gridDim.x * blockDim.x) {
        int s = esrc[k], d = edst[k];
        int pos = atomicAdd(&cursor[d], 1);
        csr_src[rowptr[d] + pos] = s;
    }
}

// ------- GEMM: h[N,128] = x[N,128] @ W[128,128], fused alpha1 dots -------
// Inner loop: R3-proven structure (scalar sX reads, float4 sW read, unroll 4).
__global__ __launch_bounds__(256) void k_gemm128(const float* __restrict__ x,
                                                 const float* __restrict__ W,
                                                 const float* __restrict__ avs,
                                                 const float* __restrict__ avd,
                                                 float* __restrict__ h,
                                                 float* __restrict__ as, float* __restrict__ ad,
                                                 int N) {
    __shared__ float sW[128 * 128];
    __shared__ float sX[32 * 128];
    int tid = threadIdx.x;
    const float4* W4 = (const float4*)W;
    float4* sW4 = (float4*)sW;
#pragma unroll
    for (int i = 0; i < 16; ++i) sW4[tid + i * 256] = W4[tid + i * 256];

    int row0 = blockIdx.x * 32;
    int lr = tid >> 5;       // 0..7
    int lk = tid & 31;       // float4 index within row
    const float4* x4 = (const float4*)x;
    float4* sX4 = (float4*)sX;
#pragma unroll
    for (int i = 0; i < 4; ++i) {
        int r = lr + i * 8;
        int gr = row0 + r; if (gr > N - 1) gr = N - 1;
        sX4[r * 32 + lk] = x4[gr * 32 + lk];
    }
    __syncthreads();

    int tr = (tid >> 5) * 4;    // 4 rows
    int tc = (tid & 31) * 4;    // 4 cols
    float acc[4][4] = {};
#pragma unroll 4
    for (int k = 0; k < 128; ++k) {
        float4 w = *(const float4*)&sW[k * 128 + tc];
#pragma unroll
        for (int i = 0; i < 4; ++i) {
            float xv = sX[(tr + i) * 128 + k];
            acc[i][0] += xv * w.x; acc[i][1] += xv * w.y;
            acc[i][2] += xv * w.z; acc[i][3] += xv * w.w;
        }
    }
    float4 vs = *(const float4*)&avs[tc];
    float4 vd = *(const float4*)&avd[tc];
#pragma unroll
    for (int i = 0; i < 4; ++i) {
        int gr = row0 + tr + i;
        if (gr < N) {
            float4 o; o.x = acc[i][0]; o.y = acc[i][1]; o.z = acc[i][2]; o.w = acc[i][3];
            *(float4*)&h[gr * 128 + tc] = o;
        }
        float ps = acc[i][0]*vs.x + acc[i][1]*vs.y + acc[i][2]*vs.z + acc[i][3]*vs.w;
        float pd = acc[i][0]*vd.x + acc[i][1]*vd.y + acc[i][2]*vd.z + acc[i][3]*vd.w;
#pragma unroll
        for (int off = 16; off; off >>= 1) {
            ps += __shfl_xor(ps, off);
            pd += __shfl_xor(pd, off);
        }
        if ((tid & 31) == 0 && gr < N) { as[gr] = ps; ad[gr] = pd; }
    }
}

// ---- layer-1 aggregation + ReLU + GEMM16 + alpha2, one wave per dst node ----
__global__ __launch_bounds__(256) void k_agg128f(const float* __restrict__ h,
                                                 const float* __restrict__ as,
                                                 const float* __restrict__ ad,
                                                 const float* __restrict__ b1,
                                                 const float* __restrict__ W2,
                                                 const float* __restrict__ avs2,
                                                 const float* __restrict__ avd2,
                                                 const int* __restrict__ rowptr,
                                                 const int* __restrict__ csr_src,
                                                 float* __restrict__ h2,
                                                 float* __restrict__ as2, float* __restrict__ ad2,
                                                 int N) {
    __shared__ float gbuf[4][128];
    int wid = (blockIdx.x * blockDim.x + threadIdx.x) >> 6;
    int lane = threadIdx.x & 63;
    int wib = threadIdx.x >> 6;
    if (wid >= N) return;
    int start = rowptr[wid], end = rowptr[wid + 1];
    int deg = end - start;                 // real in-edges (self-loop handled inline)
    float adv = ad[wid];

    // per-lane edge (first 64)
    int s_l = 0; float e_l = -1e30f;
    if (lane < deg) {
        s_l = csr_src[start + lane];
        float e = as[s_l] + adv;
        e_l = e > 0.f ? e : LEAK * e;
    }
    // max over all edges
    float m = e_l;
    for (int j = start + 64 + lane; j < end; j += 64) {
        int s = csr_src[j];
        float e = as[s] + adv;
        e = e > 0.f ? e : LEAK * e;
        m = fmaxf(m, e);
    }
#pragma unroll
    for (int off = 32; off; off >>= 1) m = fmaxf(m, __shfl_xor(m, off));
    float es = as[wid] + adv;              // self-loop score
    es = es > 0.f ? es : LEAK * es;
    m = fmaxf(m, es);

    // all 64 exps in one vector op; denom by butterfly (inactive lanes -> 0)
    float w_l = __expf(e_l - m);
    float dsum = w_l;
#pragma unroll
    for (int off = 32; off; off >>= 1) dsum += __shfl_xor(dsum, off);

    const float2* hrow = (const float2*)h;     // rows of 64 float2
    float2 a0 = make_float2(0.f, 0.f), a1 = a0, a2 = a0, a3 = a0;
    int dmain = deg < 64 ? deg : 64;
    int j = 0;
    for (; j + 4 <= dmain; j += 4) {
        int s0 = __builtin_amdgcn_readlane(s_l, j);
        int s1 = __builtin_amdgcn_readlane(s_l, j + 1);
        int s2 = __builtin_amdgcn_readlane(s_l, j + 2);
        int s3 = __builtin_amdgcn_readlane(s_l, j + 3);
        float w0 = readlane_f(w_l, j);
        float w1 = readlane_f(w_l, j + 1);
        float w2 = readlane_f(w_l, j + 2);
        float w3 = readlane_f(w_l, j + 3);
        float2 v0 = hrow[(size_t)s0 * 64 + lane];
        float2 v1 = hrow[(size_t)s1 * 64 + lane];
        float2 v2 = hrow[(size_t)s2 * 64 + lane];
        float2 v3 = hrow[(size_t)s3 * 64 + lane];
        a0.x += w0 * v0.x; a0.y += w0 * v0.y;
        a1.x += w1 * v1.x; a1.y += w1 * v1.y;
        a2.x += w2 * v2.x; a2.y += w2 * v2.y;
        a3.x += w3 * v3.x; a3.y += w3 * v3.y;
    }
    for (; j < dmain; ++j) {
        int s0 = __builtin_amdgcn_readlane(s_l, j);
        float w0 = readlane_f(w_l, j);
        float2 v0 = hrow[(size_t)s0 * 64 + lane];
        a0.x += w0 * v0.x; a0.y += w0 * v0.y;
    }
    // tail edges beyond 64 (rare)
    for (int jj = start + 64; jj < end; ++jj) {
        int s = csr_src[jj];               // wave-uniform
        float e = as[s] + adv;
        e = e > 0.f ? e : LEAK * e;
        float w = __expf(e - m);
        dsum += w;
        float2 v = hrow[(size_t)s * 64 + lane];
        a0.x += w * v.x; a0.y += w * v.y;
    }
    // self-loop
    {
        float w = __expf(es - m);
        dsum += w;
        float2 v = hrow[(size_t)wid * 64 + lane];
        a0.x += w * v.x; a0.y += w * v.y;
    }
    float accx = (a0.x + a1.x) + (a2.x + a3.x);
    float accy = (a0.y + a1.y) + (a2.y + a3.y);

    float inv = 1.0f / dsum;
    float2 bb = ((const float2*)b1)[lane];
    float gx = fmaxf(accx * inv + bb.x, 0.f);   // fused ReLU
    float gy = fmaxf(accy * inv + bb.y, 0.f);
    ((float2*)gbuf[wib])[lane] = make_float2(gx, gy);

    // h2 row = g @ W2 (128x16): lane = (q<<4)|c
    int q = lane >> 4, c = lane & 15;
    float p = 0.f;
#pragma unroll
    for (int kk = 0; kk < 32; ++kk) {
        int k = kk * 4 + q;
        p += gbuf[wib][k] * W2[k * 16 + c];
    }
    p += __shfl_xor(p, 16);
    p += __shfl_xor(p, 32);          // all lanes: h2 value for col c
    if (lane < 16) h2[wid * 16 + c] = p;
    float ps = p * avs2[c];
    float pd = p * avd2[c];
#pragma unroll
    for (int off = 8; off; off >>= 1) {
        ps += __shfl_xor(ps, off);
        pd += __shfl_xor(pd, off);
    }
    if (lane == 0) { as2[wid] = ps; ad2[wid] = pd; }
}

// ---- layer-2 aggregation: 16 lanes per node, serial over edges ----
__global__ __launch_bounds__(256) void k_agg16(const float* __restrict__ h2,
                                               const float* __restrict__ as,
                                               const float* __restrict__ ad,
                                               const float* __restrict__ bias,
                                               const int* __restrict__ rowptr,
                                               const int* __restrict__ csr_src,
                                               float* __restrict__ out, int N) {
    int grp = (blockIdx.x * blockDim.x + threadIdx.x) >> 4;  // node id
    int c = threadIdx.x & 15;
    if (grp >= N) return;
    int start = rowptr[grp], end = rowptr[grp + 1];
    float adv = ad[grp];
    float es = as[grp] + adv;              // self-loop
    es = es > 0.f ? es : LEAK * es;
    float m = es;
    for (int j = start; j < end; ++j) {
        int s = csr_src[j];                // broadcast across 16 lanes
        float e = as[s] + adv;
        e = e > 0.f ? e : LEAK * e;
        m = fmaxf(m, e);
    }
    float ws = __expf(es - m);
    float dsum = ws;
    float acc = ws * h2[grp * 16 + c];
    for (int j = start; j < end; ++j) {
        int s = csr_src[j];
        float e = as[s] + adv;
        e = e > 0.f ? e : LEAK * e;
        float w = __expf(e - m);
        dsum += w;
        acc += w * h2[s * 16 + c];
    }
    out[grp * 16 + c] = acc / dsum + bias[c];
}

extern "C" void kernel_launch(void* const* d_in, const int* in_sizes, int n_in,
                              void* d_out, int out_size, void* d_ws, size_t ws_size,
                              hipStream_t stream) {
    const float* x    = (const float*)d_in[0];
    const int*   ei   = (const int*)d_in[1];
    const float* W1   = (const float*)d_in[2];
    const float* avs1 = (const float*)d_in[3];
    const float* avd1 = (const float*)d_in[4];
    const float* b1   = (const float*)d_in[5];
    const float* W2   = (const float*)d_in[6];
    const float* avs2 = (const float*)d_in[7];
    const float* avd2 = (const float*)d_in[8];
    const float* b2   = (const float*)d_in[9];

    int N = in_sizes[0] / 128;
    int E = in_sizes[1] / 2;
    const int* esrc = ei;
    const int* edst = ei + E;

    char* p = (char*)d_ws;
    auto carve = [&](size_t bytes) { char* r = p; p += align256(bytes); return r; };
    float* h1     = (float*)carve(sizeof(float) * (size_t)N * 128);
    float* h2     = (float*)carve(sizeof(float) * (size_t)N * 16);
    float* as1    = (float*)carve(sizeof(float) * N);
    float* ad1    = (float*)carve(sizeof(float) * N);
    float* as2    = (float*)carve(sizeof(float) * N);
    float* ad2    = (float*)carve(sizeof(float) * N);
    int* rowptr   = (int*)carve(sizeof(int) * (N + 1));
    int* degcur   = (int*)carve(sizeof(int) * 2 * (size_t)N);
    int* deg = degcur; int* cursor = degcur + N;
    int* partial  = (int*)carve(sizeof(int) * 1024);
    int* csr_src  = (int*)carve(sizeof(int) * (size_t)E);

    hipMemsetAsync(degcur, 0, sizeof(int) * 2 * (size_t)N, stream);
    k_count<<<2048, 256, 0, stream>>>(edst, E, deg);

    int B = (N + 255) / 256;
    k_scan_partial<<<B, 256, 0, stream>>>(deg, N, partial);
    k_scan_top<<<1, 1024, 0, stream>>>(partial, B);
    k_scan_final<<<B, 256, 0, stream>>>(deg, N, partial, rowptr);

    k_scatter<<<2048, 256, 0, stream>>>(esrc, edst, E, rowptr, cursor, csr_src);

    int gGemm = (N + 31) / 32;
    k_gemm128<<<gGemm, 256, 0, stream>>>(x, W1, avs1, avd1, h1, as1, ad1, N);
    int gWave = (N * 64 + 255) / 256;
    k_agg128f<<<gWave, 256, 0, stream>>>(h1, as1, ad1, b1, W2, avs2, avd2,
                                         rowptr, csr_src, h2, as2, ad2, N);
    int gAgg16 = (N * 16 + 255) / 256;
    k_agg16<<<gAgg16, 256, 0, stream>>>(h2, as2, ad2, b2, rowptr, csr_src, (float*)d_out, N);
}

// Round 7
// 200.785 us; speedup vs baseline: 3.1203x; 1.1219x over previous
//
#include <hip/hip_runtime.h>
#include <hip/hip_fp16.h>

#define LEAK 0.2f
typedef unsigned int u32;

static inline size_t align256(size_t x) { return (x + 255) & ~size_t(255); }

__device__ inline float readlane_f(float v, int l) {
    return __uint_as_float((unsigned)__builtin_amdgcn_readlane(__float_as_uint(v), l));
}
__device__ inline float h16lo(u32 v) {
    return __half2float(__ushort_as_half((unsigned short)(v & 0xffffu)));
}
__device__ inline float h16hi(u32 v) {
    return __half2float(__ushort_as_half((unsigned short)(v >> 16)));
}

// ---------------- CSR build (real edges only; self-loops handled analytically) ----------------
__global__ void k_count(const int* __restrict__ edst, int E, int* __restrict__ deg) {
    for (int k = blockIdx.x * blockDim.x + threadIdx.x; k < E; k += gridDim.x * blockDim.x)
        atomicAdd(&deg[edst[k]], 1);
}

__global__ __launch_bounds__(256) void k_scan_partial(const int* __restrict__ deg, int N,
                                                      int* __restrict__ partial) {
    __shared__ int red[4];
    int i = blockIdx.x * 256 + threadIdx.x;
    int v = (i < N) ? deg[i] : 0;
#pragma unroll
    for (int off = 32; off; off >>= 1) v += __shfl_xor(v, off);
    int lane = threadIdx.x & 63, w = threadIdx.x >> 6;
    if (lane == 0) red[w] = v;
    __syncthreads();
    if (threadIdx.x == 0) partial[blockIdx.x] = red[0] + red[1] + red[2] + red[3];
}

__global__ __launch_bounds__(1024) void k_scan_top(int* __restrict__ partial, int B) {
    __shared__ int buf[1024];
    int tid = threadIdx.x;
    int v = (tid < B) ? partial[tid] : 0;
    buf[tid] = v;
    __syncthreads();
    for (int off = 1; off < 1024; off <<= 1) {
        int t = buf[tid];
        int add = (tid >= off) ? buf[tid - off] : 0;
        __syncthreads();
        buf[tid] = t + add;
        __syncthreads();
    }
    if (tid < B) partial[tid] = buf[tid] - v;   // exclusive
}

__global__ __launch_bounds__(256) void k_scan_final(const int* __restrict__ deg, int N,
                                                    const int* __restrict__ partial,
                                                    int* __restrict__ rowptr) {
    __shared__ int buf[256];
    int tid = threadIdx.x;
    int i = blockIdx.x * 256 + tid;
    int v = (i < N) ? deg[i] : 0;
    buf[tid] = v;
    __syncthreads();
    for (int off = 1; off < 256; off <<= 1) {
        int t = buf[tid];
        int add = (tid >= off) ? buf[tid - off] : 0;
        __syncthreads();
        buf[tid] = t + add;
        __syncthreads();
    }
    if (i < N) rowptr[i + 1] = partial[blockIdx.x] + buf[tid];
    if (i == 0) rowptr[0] = 0;
}

__global__ void k_scatter(const int* __restrict__ esrc, const int* __restrict__ edst,
                          int E, const int* __restrict__ rowptr,
                          int* __restrict__ cursor, int* __restrict__ csr_src) {
    for (int k = blockIdx.x * blockDim.x + threadIdx.x; k < E; k += gridDim.x * blockDim.x) {
        int s = esrc[k], d = edst[k];
        int pos = atomicAdd(&cursor[d], 1);
        csr_src[rowptr[d] + pos] = s;
    }
}

// ------- GEMM: h16[N,128](fp16) = x[N,128] @ W[128,128], fused alpha1 dots -------
__global__ __launch_bounds__(256) void k_gemm128(const float* __restrict__ x,
                                                 const float* __restrict__ W,
                                                 const float* __restrict__ avs,
                                                 const float* __restrict__ avd,
                                                 u32* __restrict__ h16,
                                                 float* __restrict__ as, float* __restrict__ ad,
                                                 int N) {
    __shared__ float sW[128 * 128];
    __shared__ float sX[32 * 128];
    int tid = threadIdx.x;
    const float4* W4 = (const float4*)W;
    float4* sW4 = (float4*)sW;
#pragma unroll
    for (int i = 0; i < 16; ++i) sW4[tid + i * 256] = W4[tid + i * 256];

    int row0 = blockIdx.x * 32;
    int lr = tid >> 5;       // 0..7
    int lk = tid & 31;       // float4 index within row
    const float4* x4 = (const float4*)x;
    float4* sX4 = (float4*)sX;
#pragma unroll
    for (int i = 0; i < 4; ++i) {
        int r = lr + i * 8;
        int gr = row0 + r; if (gr > N - 1) gr = N - 1;
        sX4[r * 32 + lk] = x4[gr * 32 + lk];
    }
    __syncthreads();

    int tr = (tid >> 5) * 4;    // 4 rows
    int tc = (tid & 31) * 4;    // 4 cols
    float acc[4][4] = {};
#pragma unroll 4
    for (int k = 0; k < 128; ++k) {
        float4 w = *(const float4*)&sW[k * 128 + tc];
#pragma unroll
        for (int i = 0; i < 4; ++i) {
            float xv = sX[(tr + i) * 128 + k];
            acc[i][0] += xv * w.x; acc[i][1] += xv * w.y;
            acc[i][2] += xv * w.z; acc[i][3] += xv * w.w;
        }
    }
    float4 vs = *(const float4*)&avs[tc];
    float4 vd = *(const float4*)&avd[tc];
#pragma unroll
    for (int i = 0; i < 4; ++i) {
        int gr = row0 + tr + i;
        if (gr < N) {
            __half2 p0 = __floats2half2_rn(acc[i][0], acc[i][1]);
            __half2 p1 = __floats2half2_rn(acc[i][2], acc[i][3]);
            uint2 pk;
            pk.x = *reinterpret_cast<u32*>(&p0);
            pk.y = *reinterpret_cast<u32*>(&p1);
            *reinterpret_cast<uint2*>(&h16[(size_t)gr * 64 + (tid & 31) * 2]) = pk;
        }
        float ps = acc[i][0]*vs.x + acc[i][1]*vs.y + acc[i][2]*vs.z + acc[i][3]*vs.w;
        float pd = acc[i][0]*vd.x + acc[i][1]*vd.y + acc[i][2]*vd.z + acc[i][3]*vd.w;
#pragma unroll
        for (int off = 16; off; off >>= 1) {
            ps += __shfl_xor(ps, off);
            pd += __shfl_xor(pd, off);
        }
        if ((tid & 31) == 0 && gr < N) { as[gr] = ps; ad[gr] = pd; }
    }
}

// ---- layer-1 aggregation (fp16 h gather) + ReLU + GEMM16 + alpha2, one wave/node ----
__global__ __launch_bounds__(256) void k_agg128f(const u32* __restrict__ hu,
                                                 const float* __restrict__ as,
                                                 const float* __restrict__ ad,
                                                 const float* __restrict__ b1,
                                                 const float* __restrict__ W2,
                                                 const float* __restrict__ avs2,
                                                 const float* __restrict__ avd2,
                                                 const int* __restrict__ rowptr,
                                                 const int* __restrict__ csr_src,
                                                 float* __restrict__ h2,
                                                 float* __restrict__ as2, float* __restrict__ ad2,
                                                 int N) {
    __shared__ float gbuf[4][128];
    int wid = (blockIdx.x * blockDim.x + threadIdx.x) >> 6;
    int lane = threadIdx.x & 63;
    int wib = threadIdx.x >> 6;
    if (wid >= N) return;
    int start = rowptr[wid], end = rowptr[wid + 1];
    int deg = end - start;                 // real in-edges (self-loop handled inline)
    float adv = ad[wid];

    int s_l = 0; float e_l = -1e30f;
    if (lane < deg) {
        s_l = csr_src[start + lane];
        float e = as[s_l] + adv;
        e_l = e > 0.f ? e : LEAK * e;
    }
    float m = e_l;
    for (int j = start + 64 + lane; j < end; j += 64) {
        int s = csr_src[j];
        float e = as[s] + adv;
        e = e > 0.f ? e : LEAK * e;
        m = fmaxf(m, e);
    }
#pragma unroll
    for (int off = 32; off; off >>= 1) m = fmaxf(m, __shfl_xor(m, off));
    float es = as[wid] + adv;              // self-loop score
    es = es > 0.f ? es : LEAK * es;
    m = fmaxf(m, es);

    float w_l = __expf(e_l - m);
    float dsum = w_l;
#pragma unroll
    for (int off = 32; off; off >>= 1) dsum += __shfl_xor(dsum, off);

    float2 a0 = make_float2(0.f, 0.f), a1 = a0, a2 = a0, a3 = a0;
    int dmain = deg < 64 ? deg : 64;
    int j = 0;
    for (; j + 4 <= dmain; j += 4) {
        int s0 = __builtin_amdgcn_readlane(s_l, j);
        int s1 = __builtin_amdgcn_readlane(s_l, j + 1);
        int s2 = __builtin_amdgcn_readlane(s_l, j + 2);
        int s3 = __builtin_amdgcn_readlane(s_l, j + 3);
        float w0 = readlane_f(w_l, j);
        float w1 = readlane_f(w_l, j + 1);
        float w2 = readlane_f(w_l, j + 2);
        float w3 = readlane_f(w_l, j + 3);
        u32 v0 = hu[(size_t)s0 * 64 + lane];
        u32 v1 = hu[(size_t)s1 * 64 + lane];
        u32 v2 = hu[(size_t)s2 * 64 + lane];
        u32 v3 = hu[(size_t)s3 * 64 + lane];
        a0.x += w0 * h16lo(v0); a0.y += w0 * h16hi(v0);
        a1.x += w1 * h16lo(v1); a1.y += w1 * h16hi(v1);
        a2.x += w2 * h16lo(v2); a2.y += w2 * h16hi(v2);
        a3.x += w3 * h16lo(v3); a3.y += w3 * h16hi(v3);
    }
    for (; j < dmain; ++j) {
        int s0 = __builtin_amdgcn_readlane(s_l, j);
        float w0 = readlane_f(w_l, j);
        u32 v0 = hu[(size_t)s0 * 64 + lane];
        a0.x += w0 * h16lo(v0); a0.y += w0 * h16hi(v0);
    }
    // tail edges beyond 64 (rare)
    for (int jj = start + 64; jj < end; ++jj) {
        int s = csr_src[jj];               // wave-uniform
        float e = as[s] + adv;
        e = e > 0.f ? e : LEAK * e;
        float w = __expf(e - m);
        dsum += w;
        u32 v = hu[(size_t)s * 64 + lane];
        a0.x += w * h16lo(v); a0.y += w * h16hi(v);
    }
    // self-loop
    {
        float w = __expf(es - m);
        dsum += w;
        u32 v = hu[(size_t)wid * 64 + lane];
        a0.x += w * h16lo(v); a0.y += w * h16hi(v);
    }
    float accx = (a0.x + a1.x) + (a2.x + a3.x);
    float accy = (a0.y + a1.y) + (a2.y + a3.y);

    float inv = 1.0f / dsum;
    float2 bb = ((const float2*)b1)[lane];
    float gx = fmaxf(accx * inv + bb.x, 0.f);   // fused ReLU
    float gy = fmaxf(accy * inv + bb.y, 0.f);
    ((float2*)gbuf[wib])[lane] = make_float2(gx, gy);

    // h2 row = g @ W2 (128x16): lane = (q<<4)|c
    int q = lane >> 4, c = lane & 15;
    float p = 0.f;
#pragma unroll
    for (int kk = 0; kk < 32; ++kk) {
        int k = kk * 4 + q;
        p += gbuf[wib][k] * W2[k * 16 + c];
    }
    p += __shfl_xor(p, 16);
    p += __shfl_xor(p, 32);          // all lanes: h2 value for col c
    if (lane < 16) h2[wid * 16 + c] = p;
    float ps = p * avs2[c];
    float pd = p * avd2[c];
#pragma unroll
    for (int off = 8; off; off >>= 1) {
        ps += __shfl_xor(ps, off);
        pd += __shfl_xor(pd, off);
    }
    if (lane == 0) { as2[wid] = ps; ad2[wid] = pd; }
}

// ---- layer-2 aggregation: one wave/node; 4 edges x 16 feats in the gather ----
__global__ __launch_bounds__(256) void k_agg16(const float* __restrict__ h2,
                                               const float* __restrict__ as,
                                               const float* __restrict__ ad,
                                               const float* __restrict__ bias,
                                               const int* __restrict__ rowptr,
                                               const int* __restrict__ csr_src,
                                               float* __restrict__ out, int N) {
    int wid = (blockIdx.x * blockDim.x + threadIdx.x) >> 6;
    int lane = threadIdx.x & 63;
    if (wid >= N) return;
    int start = rowptr[wid], end = rowptr[wid + 1];
    int deg = end - start;
    float adv = ad[wid];

    int s_l = 0; float e_l = -1e30f;
    if (lane < deg) {
        s_l = csr_src[start + lane];
        float e = as[s_l] + adv;
        e_l = e > 0.f ? e : LEAK * e;
    }
    float m = e_l;
    for (int j = start + 64 + lane; j < end; j += 64) {
        int s = csr_src[j];
        float e = as[s] + adv;
        e = e > 0.f ? e : LEAK * e;
        m = fmaxf(m, e);
    }
#pragma unroll
    for (int off = 32; off; off >>= 1) m = fmaxf(m, __shfl_xor(m, off));
    float es = as[wid] + adv;
    es = es > 0.f ? es : LEAK * es;
    m = fmaxf(m, es);

    float w_l = __expf(e_l - m);
    float dsum = w_l;
#pragma unroll
    for (int off = 32; off; off >>= 1) dsum += __shfl_xor(dsum, off);
    float ws = __expf(es - m);
    dsum += ws;                       // uniform across lanes

    int j4 = lane >> 4, c = lane & 15;
    float acc = (j4 == 0) ? ws * h2[(size_t)wid * 16 + c] : 0.f;   // self-loop once
    int dmain = deg < 64 ? deg : 64;
    int T = (dmain + 3) >> 2;
    for (int it = 0; it < T; ++it) {
        int jj = it * 4 + j4;
        int s = __shfl(s_l, jj);
        float w = __shfl(w_l, jj);
        if (jj >= dmain) w = 0.f;     // guard wrap + inactive slots
        acc += w * h2[(size_t)s * 16 + c];
    }
    // tail edges beyond 64 (rare): group 0 only
    for (int jj = start + 64; jj < end; ++jj) {
        int s = csr_src[jj];
        float e = as[s] + adv;
        e = e > 0.f ? e : LEAK * e;
        float w = __expf(e - m);
        if (j4 == 0) { acc += w * h2[(size_t)s * 16 + c]; dsum += w; }
    }
    acc += __shfl_xor(acc, 16);
    acc += __shfl_xor(acc, 32);
    if (lane < 16) out[(size_t)wid * 16 + c] = acc / dsum + bias[c];
}

extern "C" void kernel_launch(void* const* d_in, const int* in_sizes, int n_in,
                              void* d_out, int out_size, void* d_ws, size_t ws_size,
                              hipStream_t stream) {
    const float* x    = (const float*)d_in[0];
    const int*   ei   = (const int*)d_in[1];
    const float* W1   = (const float*)d_in[2];
    const float* avs1 = (const float*)d_in[3];
    const float* avd1 = (const float*)d_in[4];
    const float* b1   = (const float*)d_in[5];
    const float* W2   = (const float*)d_in[6];
    const float* avs2 = (const float*)d_in[7];
    const float* avd2 = (const float*)d_in[8];
    const float* b2   = (const float*)d_in[9];

    int N = in_sizes[0] / 128;
    int E = in_sizes[1] / 2;
    const int* esrc = ei;
    const int* edst = ei + E;

    char* p = (char*)d_ws;
    auto carve = [&](size_t bytes) { char* r = p; p += align256(bytes); return r; };
    u32*   h16    = (u32*)carve(sizeof(u32) * (size_t)N * 64);   // fp16 h1, 2 cols/dword
    float* h2     = (float*)carve(sizeof(float) * (size_t)N * 16);
    float* as1    = (float*)carve(sizeof(float) * N);
    float* ad1    = (float*)carve(sizeof(float) * N);
    float* as2    = (float*)carve(sizeof(float) * N);
    float* ad2    = (float*)carve(sizeof(float) * N);
    int* rowptr   = (int*)carve(sizeof(int) * (N + 1));
    int* degcur   = (int*)carve(sizeof(int) * 2 * (size_t)N);
    int* deg = degcur; int* cursor = degcur + N;
    int* partial  = (int*)carve(sizeof(int) * 1024);
    int* csr_src  = (int*)carve(sizeof(int) * (size_t)E);

    hipMemsetAsync(degcur, 0, sizeof(int) * 2 * (size_t)N, stream);
    k_count<<<2048, 256, 0, stream>>>(edst, E, deg);

    int B = (N + 255) / 256;
    k_scan_partial<<<B, 256, 0, stream>>>(deg, N, partial);
    k_scan_top<<<1, 1024, 0, stream>>>(partial, B);
    k_scan_final<<<B, 256, 0, stream>>>(deg, N, partial, rowptr);

    k_scatter<<<2048, 256, 0, stream>>>(esrc, edst, E, rowptr, cursor, csr_src);

    int gGemm = (N + 31) / 32;
    k_gemm128<<<gGemm, 256, 0, stream>>>(x, W1, avs1, avd1, h16, as1, ad1, N);
    int gWave = (N * 64 + 255) / 256;
    k_agg128f<<<gWave, 256, 0, stream>>>(h16, as1, ad1, b1, W2, avs2, avd2,
                                         rowptr, csr_src, h2, as2, ad2, N);
    k_agg16<<<gWave, 256, 0, stream>>>(h2, as2, ad2, b2, rowptr, csr_src, (float*)d_out, N);
}